// Round 7
// baseline (1252.894 us; speedup 1.0000x reference)
//
#include <hip/hip_runtime.h>
#include <hip/hip_fp16.h>
#include <stdint.h>

typedef uint32_t u32;
typedef uint64_t u64;
typedef unsigned int v4u __attribute__((ext_vector_type(4)));
typedef float v4f __attribute__((ext_vector_type(4)));

constexpr int CB   = 8192;   // batch
constexpr int CG   = 689;    // genes
constexpr int CL   = 6;      // scanned layers
constexpr int CS   = 2785;   // layer width
constexpr int CSP  = 2816;   // padded width for tables
constexpr int CRS  = 8256;   // row stride (elements); 16512 B, 16B-aligned, not 4KB-periodic
constexpr int KCAP = 112;    // max nnz per column (mean 55.7, sd 7.4 -> +7.6 sigma), mult of 8
constexpr int RCAP = 112;    // max nnz per row (same distribution)

union V16 { v4u u; _Float16 h[8]; };
union F4  { v4f v; float f[4]; u32 u[4]; };
union HW  { u32 u; _Float16 h[2]; };

// ---- phase A: per-row CSR slab, LDS counter (no global atomics) ----
// one block per (l,j) row; entry u32 = (s<<16) | half(w)
__global__ __launch_bounds__(256) void build_csr(const float* __restrict__ lm,
                                                 const float* __restrict__ W,
                                                 u32* __restrict__ slab,
                                                 int* __restrict__ rcnt)
{
    int rb = blockIdx.x;                 // l*CS + j
    const float* lrow = lm + (size_t)rb * CS;
    const float* wrow = W  + (size_t)rb * CS;
    u32* out = slab + (size_t)rb * RCAP;
    __shared__ int lc;
    if (threadIdx.x == 0) lc = 0;
    __syncthreads();

    for (int s4 = threadIdx.x * 4; s4 < CS; s4 += 1024) {
        if (s4 + 4 <= CS) {
            F4 m4; m4.v = *reinterpret_cast<const v4f*>(lrow + s4);
            if ((m4.u[0] | m4.u[1] | m4.u[2] | m4.u[3]) == 0u) continue;
            F4 w4; w4.v = *reinterpret_cast<const v4f*>(wrow + s4);
#pragma unroll
            for (int q = 0; q < 4; q++) {
                if (m4.f[q] != 0.0f) {
                    int pos = atomicAdd(&lc, 1);
                    if (pos < RCAP) {
                        u32 hw = (u32)__half_as_ushort(__float2half(w4.f[q]));
                        out[pos] = ((u32)(s4 + q) << 16) | hw;
                    }
                }
            }
        } else {
            for (int s = s4; s < CS; s++) {
                if (lrow[s] != 0.0f) {
                    int pos = atomicAdd(&lc, 1);
                    if (pos < RCAP) {
                        u32 hw = (u32)__half_as_ushort(__float2half(wrow[s]));
                        out[pos] = ((u32)s << 16) | hw;
                    }
                }
            }
        }
    }
    __syncthreads();
    if (threadIdx.x == 0) rcnt[rb] = (lc < RCAP) ? lc : RCAP;
}

// ---- phase B: CSR slab -> CSC tables (atomic append, tiny coalesced reads) ----
__global__ __launch_bounds__(256) void build_csc(const u32* __restrict__ slab,
                                                 const int* __restrict__ rcnt,
                                                 u64* __restrict__ ent,
                                                 int* __restrict__ cnt)
{
    int i = blockIdx.x * 256 + threadIdx.x;
    if (i >= CL * CS * RCAP) return;
    int row = i / RCAP;
    int pos = i - row * RCAP;
    if (pos >= rcnt[row]) return;
    u32 e = slab[i];
    int l = row / CS;
    int j = row - l * CS;
    u32 hw = e & 0xffffu;
    int col = l * CSP + (int)(e >> 16);
    int p = atomicAdd(&cnt[col], 1);
    if (p < KCAP) {
        u64 hi = ((u64)((u32)j * (u32)(CRS * 2))) << 32;
        ent[(size_t)col * KCAP + p] = hi | (u64)(hw | (hw << 16));
    }
}

// ---- depth-0 table from W0 * lm0 (row j per block; tiny) ----
__global__ __launch_bounds__(256) void build0(const float* __restrict__ lm0,
                                              const float* __restrict__ W0,
                                              u64* __restrict__ ent,
                                              int* __restrict__ cnt)
{
    int j = blockIdx.x;
    const float* lrow = lm0 + (size_t)j * CS;
    const float* wrow = W0  + (size_t)j * CS;
    u64 hi = ((u64)((u32)j * (u32)(CRS * 2))) << 32;
    for (int s = threadIdx.x; s < CS; s += 256) {
        if (lrow[s] != 0.0f) {
            int pos = atomicAdd(&cnt[s], 1);
            if (pos < KCAP) {
                u32 hw = (u32)__half_as_ushort(__float2half(wrow[s]));
                ent[(size_t)s * KCAP + pos] = hi | (u64)(hw | (hw << 16));
            }
        }
    }
}

// ---- x [B,G] fp32 -> xT [G, CRS] fp16 ----
__global__ __launch_bounds__(256) void transpose_x(const float* __restrict__ x,
                                                   __half* __restrict__ xT)
{
    __shared__ float tile[32][33];
    int gx = blockIdx.x * 32;
    int gy = blockIdx.y * 32;
    int tx = threadIdx.x, ty = threadIdx.y;
#pragma unroll
    for (int i = 0; i < 32; i += 8) {
        int g = gx + tx;
        int b = gy + ty + i;
        tile[ty + i][tx] = (g < CG) ? x[(size_t)b * CG + g] : 0.f;
    }
    __syncthreads();
#pragma unroll
    for (int i = 0; i < 32; i += 8) {
        int g = gx + ty + i;
        int b = gy + tx;
        if (g < CG) xT[(size_t)g * CRS + b] = __float2half(tile[tx][ty + i]);
    }
}

// ---- sparse masked-linear ----
// grid (8, NC, 2), block 64 (1 wave). linear%8 = blockIdx.x -> XCD k owns batch
// chunk k (z=0 wave of blocks drains before z=1): per-XCD src slice 2.85 MB < 4 MB L2.
// Entries processed in full groups of 8 + masked tail (ent region is NOT zeroed:
// ws is re-poisoned 0xAA, so tail slots are garbage and must be masked).
// MACs written as fmaf(f32, (float)f16, f32) to invite v_fma_mix fusion.
__global__ __launch_bounds__(64) void gather_k(const __half* __restrict__ src,
                                               __half* __restrict__ dst,
                                               const u64* __restrict__ ent,
                                               const int* __restrict__ cnt,
                                               const float* __restrict__ bias,
                                               float* __restrict__ sumv,
                                               float* __restrict__ sumq,
                                               const int* __restrict__ sel,
                                               const int* __restrict__ selcnt)
{
    int s;
    if (sel) {
        if ((int)blockIdx.y >= *selcnt) return;
        s = sel[blockIdx.y];
    } else {
        s = blockIdx.y;
    }
    int lane = threadIdx.x;
    int boff = blockIdx.z * 4096 + blockIdx.x * 512 + lane * 8;

    int n = cnt[s]; if (n > KCAP) n = KCAP;
    int ngf = n >> 3;                      // full groups of 8
    int rem = n & 7;
    const u64* e = ent + (size_t)s * KCAP;
    const char* sb = (const char*)src + (size_t)boff * 2;

    float bv = bias[s];
    float acc[8];
#pragma unroll
    for (int j = 0; j < 8; j++) acc[j] = bv;

    for (int g = 0; g < ngf; g++) {
        u64 ev[8];
#pragma unroll
        for (int q = 0; q < 8; q++) ev[q] = e[g * 8 + q];
        V16 rv[8];
#pragma unroll
        for (int q = 0; q < 8; q++)
            rv[q].u = *reinterpret_cast<const v4u*>(sb + (u32)(ev[q] >> 32));
#pragma unroll
        for (int q = 0; q < 8; q++) {
            HW w2; w2.u = (u32)ev[q];
            float wf = (float)w2.h[0];
#pragma unroll
            for (int j = 0; j < 8; j++)
                acc[j] = fmaf(wf, (float)rv[q].h[j], acc[j]);
        }
    }
    if (rem) {
        int base = ngf * 8;
        u64 ev[8];
#pragma unroll
        for (int q = 0; q < 8; q++) ev[q] = e[base + q];
        V16 rv[8];
#pragma unroll
        for (int q = 0; q < 8; q++) {
            u32 off = (q < rem) ? (u32)(ev[q] >> 32) : 0u;
            rv[q].u = *reinterpret_cast<const v4u*>(sb + off);
        }
#pragma unroll
        for (int q = 0; q < 8; q++) {
            HW w2; w2.u = (u32)ev[q];
            float wf = (q < rem) ? (float)w2.h[0] : 0.f;
#pragma unroll
            for (int j = 0; j < 8; j++)
                acc[j] = fmaf(wf, (float)rv[q].h[j], acc[j]);
        }
    }

    V16 o;
#pragma unroll
    for (int j = 0; j < 8; j++) o.h[j] = (_Float16)acc[j];
    __builtin_nontemporal_store(o.u, reinterpret_cast<v4u*>(dst + (size_t)s * CRS + boff));

    float ls = 0.f, lq = 0.f;
#pragma unroll
    for (int j = 0; j < 8; j++) { ls += acc[j]; lq += acc[j] * acc[j]; }
#pragma unroll
    for (int off = 32; off > 0; off >>= 1) {
        ls += __shfl_xor(ls, off);
        lq += __shfl_xor(lq, off);
    }
    if (lane == 0) { atomicAdd(&sumv[s], ls); atomicAdd(&sumq[s], lq); }
}

// ---- finalize BN stats + tanh + diagonal skip (in place) ----
// grid (8, CS, 2), z REVERSED: processes batch-half 1 then 0, so the half the
// next gather reads first ([0,4096)) is the last written -> L2-resident handoff.
__global__ __launch_bounds__(64) void bn_act(__half* __restrict__ h,
                                             const __half* __restrict__ prev,
                                             const float* __restrict__ sumv,
                                             const float* __restrict__ sumq,
                                             const float* __restrict__ gamma,
                                             const float* __restrict__ beta,
                                             const float* __restrict__ dlv)
{
    int s = blockIdx.y;
    int boff = (1 - (int)blockIdx.z) * 4096 + blockIdx.x * 512 + threadIdx.x * 8;
    float mean = sumv[s] * (1.0f / CB);
    float var  = sumq[s] * (1.0f / CB) - mean * mean;
    float rstd = rsqrtf(var + 1e-5f);
    float scale = gamma[s] * rstd;
    float shift = beta[s] - mean * scale;
    size_t base = (size_t)s * CRS + boff;
    V16 v; v.u = *reinterpret_cast<const v4u*>(h + base);
    V16 pv;
    float d = 0.f;
    if (prev) { d = dlv[s]; pv.u = *reinterpret_cast<const v4u*>(prev + base); }
    V16 o;
#pragma unroll
    for (int j = 0; j < 8; j++) {
        float t = tanhf(fmaf((float)v.h[j], scale, shift));
        if (prev) t = fmaf(d, (float)pv.h[j], t);
        o.h[j] = (_Float16)t;
    }
    *reinterpret_cast<v4u*>(h + base) = o.u;
}

// ---- head prep: compact nonzero fasm[s]*w_out[s] into (s,c) list ----
__global__ __launch_bounds__(256) void head_prep(const float* __restrict__ fasm,
                                                 const float* __restrict__ wout,
                                                 int* __restrict__ hcnt,
                                                 int* __restrict__ hs,
                                                 float* __restrict__ hc)
{
    int s = blockIdx.x * 256 + threadIdx.x;
    if (s >= CS) return;
    float c = fasm[s] * wout[s];
    if (c != 0.f) {
        int p = atomicAdd(hcnt, 1);
        if (p < 64) { hs[p] = s; hc[p] = c; }
    }
}

// ---- head: fused BN(layer6)+tanh+skip+dot on the selected rows only ----
__global__ __launch_bounds__(256) void head_k(const __half* __restrict__ h6pre,
                                              const __half* __restrict__ h5,
                                              const int* __restrict__ hcnt,
                                              const int* __restrict__ hs,
                                              const float* __restrict__ hc,
                                              const float* __restrict__ sumv,
                                              const float* __restrict__ sumq,
                                              const float* __restrict__ gamma,
                                              const float* __restrict__ beta,
                                              const float* __restrict__ dlv,
                                              const float* __restrict__ bout,
                                              float* __restrict__ out)
{
    int b = blockIdx.x * 256 + threadIdx.x;   // grid 32 -> 8192
    int n = *hcnt; if (n > 64) n = 64;
    float acc = bout[0];
    for (int k = 0; k < n; k++) {
        int s = hs[k];
        float mean = sumv[s] * (1.0f / CB);
        float var  = sumq[s] * (1.0f / CB) - mean * mean;
        float rstd = rsqrtf(var + 1e-5f);
        float scale = gamma[s] * rstd;
        float shift = beta[s] - mean * scale;
        float pre  = __half2float(h6pre[(size_t)s * CRS + b]);
        float prev = __half2float(h5[(size_t)s * CRS + b]);
        float hn = tanhf(fmaf(pre, scale, shift)) + dlv[s] * prev;
        acc = fmaf(hc[k], hn, acc);
    }
    out[b] = acc;
}

extern "C" void kernel_launch(void* const* d_in, const int* in_sizes, int n_in,
                              void* d_out, int out_size, void* d_ws, size_t ws_size,
                              hipStream_t stream)
{
    const float* x    = (const float*)d_in[0];
    const float* lm0  = (const float*)d_in[1];
    const float* lm   = (const float*)d_in[2];
    const float* flm  = (const float*)d_in[3];
    const float* fasm = (const float*)d_in[4];
    const float* W0   = (const float*)d_in[5];
    const float* b0   = (const float*)d_in[6];
    const float* W    = (const float*)d_in[7];
    const float* bb   = (const float*)d_in[8];
    const float* gam  = (const float*)d_in[9];
    const float* bet  = (const float*)d_in[10];
    const float* wout = (const float*)d_in[11];
    const float* bout = (const float*)d_in[12];
    float* out = (float*)d_out;

    // workspace carve (16B-aligned)
    char* ws = (char*)d_ws;
    int*    cnt  = (int*)ws;                     // 7*2816*4 = 78,848
    float*  sumv = (float*)(ws + 78848);         // 78,848
    float*  sumq = (float*)(ws + 157696);        // 78,848 -> end 236,544
    int*    hcnt = (int*)(ws + 236544);          // 16
    int*    hs   = (int*)(ws + 236560);          // 256
    float*  hc   = (float*)(ws + 236816);        // 256 -> 237,072; pad to 237,184
    int*    rcnt = (int*)(ws + 237184);          // 16,710*4 = 66,840 -> 304,024; pad 304,128
    u64*    ent  = (u64*)(ws + 304128);          // 7*2816*112*8 = 17,661,952 -> 17,966,080
    __half* hA   = (__half*)(ws + 17966080);     // 45,985,920 -> 63,952,000
    __half* hB   = (__half*)(ws + 63952000);     // 45,985,920 -> 109,937,920
    u32*    slab = (u32*)hA;                     // alias: 16,710*112*4 = 7.49 MB, dead before hA written
    __half* xT   = hB;                           // alias: xT (689 rows) dead before hB written

    (void)hipMemsetAsync(ws, 0, 237184, stream);   // cnt + sums + head counters only

    build_csr<<<dim3(CL * CS), 256, 0, stream>>>(lm, W, slab, rcnt);
    build_csc<<<dim3((CL * CS * RCAP + 255) / 256), 256, 0, stream>>>(slab, rcnt,
        ent + (size_t)CSP * KCAP, cnt + CSP);
    build0<<<dim3(CG), 256, 0, stream>>>(lm0, W0, ent, cnt);
    transpose_x<<<dim3(22, 256), dim3(32, 8), 0, stream>>>(x, xT);
    head_prep<<<dim3(11), 256, 0, stream>>>(fasm, wout, hcnt, hs, hc);

    const __half* cur = xT;
    __half* bufs[2] = {hA, hB};
    int which = 0;
    for (int t = 0; t < 6; t++) {                 // layers 0..5 full-width
        __half* dst = bufs[which];
        const float* bias = (t == 0) ? b0 : bb + (size_t)(t - 1) * CS;
        gather_k<<<dim3(8, CS, 2), 64, 0, stream>>>(cur, dst,
            ent + (size_t)t * CSP * KCAP, cnt + t * CSP, bias,
            sumv + t * CSP, sumq + t * CSP, nullptr, nullptr);
        bn_act<<<dim3(8, CS, 2), 64, 0, stream>>>(dst, (t == 0) ? nullptr : cur,
            sumv + t * CSP, sumq + t * CSP, gam + (size_t)t * CS, bet + (size_t)t * CS,
            (t == 0) ? nullptr : flm + (size_t)(t - 1) * CS);
        cur = dst;
        which ^= 1;
    }
    // layer 6: only the head's 16 selected columns
    __half* h6 = bufs[which];                     // hA; cur == hB == layer-5 output
    gather_k<<<dim3(8, 16, 2), 64, 0, stream>>>(cur, h6,
        ent + (size_t)6 * CSP * KCAP, cnt + 6 * CSP, bb + (size_t)5 * CS,
        sumv + 6 * CSP, sumq + 6 * CSP, hs, hcnt);
    head_k<<<dim3(32), 256, 0, stream>>>(h6, cur, hcnt, hs, hc,
        sumv + 6 * CSP, sumq + 6 * CSP, gam + (size_t)6 * CS, bet + (size_t)6 * CS,
        flm + (size_t)5 * CS, bout, out);
}

// Round 8
// 1249.286 us; speedup vs baseline: 1.0029x; 1.0029x over previous
//
#include <hip/hip_runtime.h>
#include <hip/hip_fp16.h>
#include <stdint.h>

typedef uint32_t u32;
typedef uint64_t u64;
typedef unsigned int v4u __attribute__((ext_vector_type(4)));
typedef float v4f __attribute__((ext_vector_type(4)));

constexpr int CB   = 8192;   // batch
constexpr int CG   = 689;    // genes
constexpr int CL   = 6;      // scanned layers
constexpr int CS   = 2785;   // layer width
constexpr int CSP  = 2816;   // padded width for tables
constexpr int CRS  = 8256;   // row stride (elements); 16512 B, 16B-aligned, not 4KB-periodic
constexpr int KCAP = 112;    // max nnz per column (mean 55.7, sd 7.4 -> +7.6 sigma), mult of 8
constexpr int RCAP = 112;    // max nnz per row (same distribution)

union V16 { v4u u; _Float16 h[8]; };
union F4  { v4f v; float f[4]; u32 u[4]; };
union HW  { u32 u; _Float16 h[2]; };

// ---- phase A: per-row CSR slab, LDS counter (no global atomics) ----
__global__ __launch_bounds__(256) void build_csr(const float* __restrict__ lm,
                                                 const float* __restrict__ W,
                                                 u32* __restrict__ slab,
                                                 int* __restrict__ rcnt)
{
    int rb = blockIdx.x;                 // l*CS + j
    const float* lrow = lm + (size_t)rb * CS;
    const float* wrow = W  + (size_t)rb * CS;
    u32* out = slab + (size_t)rb * RCAP;
    __shared__ int lc;
    if (threadIdx.x == 0) lc = 0;
    __syncthreads();

    for (int s4 = threadIdx.x * 4; s4 < CS; s4 += 1024) {
        if (s4 + 4 <= CS) {
            F4 m4; m4.v = *reinterpret_cast<const v4f*>(lrow + s4);
            if ((m4.u[0] | m4.u[1] | m4.u[2] | m4.u[3]) == 0u) continue;
            F4 w4; w4.v = *reinterpret_cast<const v4f*>(wrow + s4);
#pragma unroll
            for (int q = 0; q < 4; q++) {
                if (m4.f[q] != 0.0f) {
                    int pos = atomicAdd(&lc, 1);
                    if (pos < RCAP) {
                        u32 hw = (u32)__half_as_ushort(__float2half(w4.f[q]));
                        out[pos] = ((u32)(s4 + q) << 16) | hw;
                    }
                }
            }
        } else {
            for (int s = s4; s < CS; s++) {
                if (lrow[s] != 0.0f) {
                    int pos = atomicAdd(&lc, 1);
                    if (pos < RCAP) {
                        u32 hw = (u32)__half_as_ushort(__float2half(wrow[s]));
                        out[pos] = ((u32)s << 16) | hw;
                    }
                }
            }
        }
    }
    __syncthreads();
    if (threadIdx.x == 0) rcnt[rb] = (lc < RCAP) ? lc : RCAP;
}

// ---- phase B: CSR slab -> CSC tables (atomic append, coalesced reads) ----
__global__ __launch_bounds__(256) void build_csc(const u32* __restrict__ slab,
                                                 const int* __restrict__ rcnt,
                                                 u64* __restrict__ ent,
                                                 int* __restrict__ cnt)
{
    int i = blockIdx.x * 256 + threadIdx.x;
    if (i >= CL * CS * RCAP) return;
    int row = i / RCAP;
    int pos = i - row * RCAP;
    if (pos >= rcnt[row]) return;
    u32 e = slab[i];
    int l = row / CS;
    int j = row - l * CS;
    u32 hw = e & 0xffffu;
    int col = l * CSP + (int)(e >> 16);
    int p = atomicAdd(&cnt[col], 1);
    if (p < KCAP) {
        u64 hi = ((u64)((u32)j * (u32)(CRS * 2))) << 32;
        ent[(size_t)col * KCAP + p] = hi | (u64)(hw | (hw << 16));
    }
}

// ---- depth-0 table from W0 * lm0 ----
__global__ __launch_bounds__(256) void build0(const float* __restrict__ lm0,
                                              const float* __restrict__ W0,
                                              u64* __restrict__ ent,
                                              int* __restrict__ cnt)
{
    int j = blockIdx.x;
    const float* lrow = lm0 + (size_t)j * CS;
    const float* wrow = W0  + (size_t)j * CS;
    u64 hi = ((u64)((u32)j * (u32)(CRS * 2))) << 32;
    for (int s = threadIdx.x; s < CS; s += 256) {
        if (lrow[s] != 0.0f) {
            int pos = atomicAdd(&cnt[s], 1);
            if (pos < KCAP) {
                u32 hw = (u32)__half_as_ushort(__float2half(wrow[s]));
                ent[(size_t)s * KCAP + pos] = hi | (u64)(hw | (hw << 16));
            }
        }
    }
}

// ---- x [B,G] fp32 -> xT [G, CRS] fp16 ----
__global__ __launch_bounds__(256) void transpose_x(const float* __restrict__ x,
                                                   __half* __restrict__ xT)
{
    __shared__ float tile[32][33];
    int gx = blockIdx.x * 32;
    int gy = blockIdx.y * 32;
    int tx = threadIdx.x, ty = threadIdx.y;
#pragma unroll
    for (int i = 0; i < 32; i += 8) {
        int g = gx + tx;
        int b = gy + ty + i;
        tile[ty + i][tx] = (g < CG) ? x[(size_t)b * CG + g] : 0.f;
    }
    __syncthreads();
#pragma unroll
    for (int i = 0; i < 32; i += 8) {
        int g = gx + ty + i;
        int b = gy + tx;
        if (g < CG) xT[(size_t)g * CRS + b] = __float2half(tile[tx][ty + i]);
    }
}

// ---- sparse masked-linear, 2-stage double-buffered K-pipeline ----
// grid (8, NC, 2), block 64 (1 wave). linear%8 = blockIdx.x -> XCD-chunk affinity.
// Group g+1's 8 row-loads are issued BEFORE group g's 64 fma_mix ops, so
// L1-fill latency overlaps VALU (R7: both ~50%, serialized). Alternating
// register sets rvA/rvB -- no rotation movs (R4's mistake).
__global__ __launch_bounds__(64) void gather_k(const __half* __restrict__ src,
                                               __half* __restrict__ dst,
                                               const u64* __restrict__ ent,
                                               const int* __restrict__ cnt,
                                               const float* __restrict__ bias,
                                               float* __restrict__ sumv,
                                               float* __restrict__ sumq,
                                               const int* __restrict__ sel,
                                               const int* __restrict__ selcnt)
{
    int s;
    if (sel) {
        if ((int)blockIdx.y >= *selcnt) return;
        s = sel[blockIdx.y];
    } else {
        s = blockIdx.y;
    }
    int lane = threadIdx.x;
    int boff = blockIdx.z * 4096 + blockIdx.x * 512 + lane * 8;

    int n = cnt[s]; if (n > KCAP) n = KCAP;
    int ngf = n >> 3;                      // full groups of 8
    int rem = n & 7;
    const u64* e = ent + (size_t)s * KCAP;
    const char* sb = (const char*)src + (size_t)boff * 2;

    float bv = bias[s];
    float acc[8];
#pragma unroll
    for (int j = 0; j < 8; j++) acc[j] = bv;

    u64 evA[8], evB[8];
    V16 rvA[8], rvB[8];

#define LOADG(EV, RV, G)                                                      \
    {                                                                         \
        _Pragma("unroll")                                                     \
        for (int q = 0; q < 8; q++) EV[q] = e[(G) * 8 + q];                   \
        _Pragma("unroll")                                                     \
        for (int q = 0; q < 8; q++)                                           \
            RV[q].u = *reinterpret_cast<const v4u*>(sb + (u32)(EV[q] >> 32)); \
    }
#define COMPG(EV, RV)                                                         \
    {                                                                         \
        _Pragma("unroll")                                                     \
        for (int q = 0; q < 8; q++) {                                         \
            HW w2; w2.u = (u32)EV[q];                                         \
            float wf = (float)w2.h[0];                                        \
            _Pragma("unroll")                                                 \
            for (int j = 0; j < 8; j++)                                       \
                acc[j] = fmaf(wf, (float)RV[q].h[j], acc[j]);                 \
        }                                                                     \
    }

    int g = 0;
    if (ngf > 0) LOADG(evA, rvA, 0);
    for (; g + 2 <= ngf; g += 2) {
        LOADG(evB, rvB, g + 1);
        COMPG(evA, rvA);
        if (g + 2 < ngf) LOADG(evA, rvA, g + 2);
        COMPG(evB, rvB);
    }
    if (g < ngf) COMPG(evA, rvA);          // odd last group: rvA already loaded
#undef LOADG
#undef COMPG

    if (rem) {                             // masked tail (ent not zero-initialized)
        int base = ngf * 8;
        u64 ev[8];
#pragma unroll
        for (int q = 0; q < 8; q++) ev[q] = e[base + q];
        V16 rv[8];
#pragma unroll
        for (int q = 0; q < 8; q++) {
            u32 off = (q < rem) ? (u32)(ev[q] >> 32) : 0u;
            rv[q].u = *reinterpret_cast<const v4u*>(sb + off);
        }
#pragma unroll
        for (int q = 0; q < 8; q++) {
            HW w2; w2.u = (u32)ev[q];
            float wf = (q < rem) ? (float)w2.h[0] : 0.f;
#pragma unroll
            for (int j = 0; j < 8; j++)
                acc[j] = fmaf(wf, (float)rv[q].h[j], acc[j]);
        }
    }

    V16 o;
#pragma unroll
    for (int j = 0; j < 8; j++) o.h[j] = (_Float16)acc[j];
    __builtin_nontemporal_store(o.u, reinterpret_cast<v4u*>(dst + (size_t)s * CRS + boff));

    float ls = 0.f, lq = 0.f;
#pragma unroll
    for (int j = 0; j < 8; j++) { ls += acc[j]; lq += acc[j] * acc[j]; }
#pragma unroll
    for (int off = 32; off > 0; off >>= 1) {
        ls += __shfl_xor(ls, off);
        lq += __shfl_xor(lq, off);
    }
    if (lane == 0) { atomicAdd(&sumv[s], ls); atomicAdd(&sumq[s], lq); }
}

// ---- finalize BN stats + tanh + diagonal skip (in place); XCD-matched chunks ----
__global__ __launch_bounds__(64) void bn_act(__half* __restrict__ h,
                                             const __half* __restrict__ prev,
                                             const float* __restrict__ sumv,
                                             const float* __restrict__ sumq,
                                             const float* __restrict__ gamma,
                                             const float* __restrict__ beta,
                                             const float* __restrict__ dlv)
{
    int s = blockIdx.y;
    int boff = blockIdx.x * 512 + threadIdx.x * 8;   // chunk c -> XCD c%8, matches gather
    float mean = sumv[s] * (1.0f / CB);
    float var  = sumq[s] * (1.0f / CB) - mean * mean;
    float rstd = rsqrtf(var + 1e-5f);
    float scale = gamma[s] * rstd;
    float shift = beta[s] - mean * scale;
    size_t base = (size_t)s * CRS + boff;
    V16 v; v.u = *reinterpret_cast<const v4u*>(h + base);
    V16 pv;
    float d = 0.f;
    if (prev) { d = dlv[s]; pv.u = *reinterpret_cast<const v4u*>(prev + base); }
    V16 o;
#pragma unroll
    for (int j = 0; j < 8; j++) {
        float t = tanhf(fmaf((float)v.h[j], scale, shift));
        if (prev) t = fmaf(d, (float)pv.h[j], t);
        o.h[j] = (_Float16)t;
    }
    *reinterpret_cast<v4u*>(h + base) = o.u;
}

// ---- head prep: compact nonzero fasm[s]*w_out[s] into (s,c) list ----
__global__ __launch_bounds__(256) void head_prep(const float* __restrict__ fasm,
                                                 const float* __restrict__ wout,
                                                 int* __restrict__ hcnt,
                                                 int* __restrict__ hs,
                                                 float* __restrict__ hc)
{
    int s = blockIdx.x * 256 + threadIdx.x;
    if (s >= CS) return;
    float c = fasm[s] * wout[s];
    if (c != 0.f) {
        int p = atomicAdd(hcnt, 1);
        if (p < 64) { hs[p] = s; hc[p] = c; }
    }
}

// ---- head: fused BN(layer6)+tanh+skip+dot on the selected rows only ----
__global__ __launch_bounds__(256) void head_k(const __half* __restrict__ h6pre,
                                              const __half* __restrict__ h5,
                                              const int* __restrict__ hcnt,
                                              const int* __restrict__ hs,
                                              const float* __restrict__ hc,
                                              const float* __restrict__ sumv,
                                              const float* __restrict__ sumq,
                                              const float* __restrict__ gamma,
                                              const float* __restrict__ beta,
                                              const float* __restrict__ dlv,
                                              const float* __restrict__ bout,
                                              float* __restrict__ out)
{
    int b = blockIdx.x * 256 + threadIdx.x;   // grid 32 -> 8192
    int n = *hcnt; if (n > 64) n = 64;
    float acc = bout[0];
    for (int k = 0; k < n; k++) {
        int s = hs[k];
        float mean = sumv[s] * (1.0f / CB);
        float var  = sumq[s] * (1.0f / CB) - mean * mean;
        float rstd = rsqrtf(var + 1e-5f);
        float scale = gamma[s] * rstd;
        float shift = beta[s] - mean * scale;
        float pre  = __half2float(h6pre[(size_t)s * CRS + b]);
        float prev = __half2float(h5[(size_t)s * CRS + b]);
        float hn = tanhf(fmaf(pre, scale, shift)) + dlv[s] * prev;
        acc = fmaf(hc[k], hn, acc);
    }
    out[b] = acc;
}

extern "C" void kernel_launch(void* const* d_in, const int* in_sizes, int n_in,
                              void* d_out, int out_size, void* d_ws, size_t ws_size,
                              hipStream_t stream)
{
    const float* x    = (const float*)d_in[0];
    const float* lm0  = (const float*)d_in[1];
    const float* lm   = (const float*)d_in[2];
    const float* flm  = (const float*)d_in[3];
    const float* fasm = (const float*)d_in[4];
    const float* W0   = (const float*)d_in[5];
    const float* b0   = (const float*)d_in[6];
    const float* W    = (const float*)d_in[7];
    const float* bb   = (const float*)d_in[8];
    const float* gam  = (const float*)d_in[9];
    const float* bet  = (const float*)d_in[10];
    const float* wout = (const float*)d_in[11];
    const float* bout = (const float*)d_in[12];
    float* out = (float*)d_out;

    // workspace carve (16B-aligned)
    char* ws = (char*)d_ws;
    int*    cnt  = (int*)ws;                     // 7*2816*4 = 78,848
    float*  sumv = (float*)(ws + 78848);         // 78,848
    float*  sumq = (float*)(ws + 157696);        // 78,848 -> end 236,544
    int*    hcnt = (int*)(ws + 236544);          // 16
    int*    hs   = (int*)(ws + 236560);          // 256
    float*  hc   = (float*)(ws + 236816);        // 256 -> 237,072; pad to 237,184
    int*    rcnt = (int*)(ws + 237184);          // 16,710*4 -> 304,024; pad 304,128
    u64*    ent  = (u64*)(ws + 304128);          // 7*2816*112*8 = 17,661,952 -> 17,966,080
    __half* hA   = (__half*)(ws + 17966080);     // 45,985,920 -> 63,952,000
    __half* hB   = (__half*)(ws + 63952000);     // 45,985,920 -> 109,937,920
    u32*    slab = (u32*)hA;                     // alias: 7.49 MB, dead before hA written
    __half* xT   = hB;                           // alias: xT (689 rows) dead before hB written

    (void)hipMemsetAsync(ws, 0, 237184, stream);   // cnt + sums + head counters only

    build_csr<<<dim3(CL * CS), 256, 0, stream>>>(lm, W, slab, rcnt);
    build_csc<<<dim3((CL * CS * RCAP + 255) / 256), 256, 0, stream>>>(slab, rcnt,
        ent + (size_t)CSP * KCAP, cnt + CSP);
    build0<<<dim3(CG), 256, 0, stream>>>(lm0, W0, ent, cnt);
    transpose_x<<<dim3(22, 256), dim3(32, 8), 0, stream>>>(x, xT);
    head_prep<<<dim3(11), 256, 0, stream>>>(fasm, wout, hcnt, hs, hc);

    const __half* cur = xT;
    __half* bufs[2] = {hA, hB};
    int which = 0;
    for (int t = 0; t < 6; t++) {                 // layers 0..5 full-width
        __half* dst = bufs[which];
        const float* bias = (t == 0) ? b0 : bb + (size_t)(t - 1) * CS;
        gather_k<<<dim3(8, CS, 2), 64, 0, stream>>>(cur, dst,
            ent + (size_t)t * CSP * KCAP, cnt + t * CSP, bias,
            sumv + t * CSP, sumq + t * CSP, nullptr, nullptr);
        bn_act<<<dim3(16, CS), 64, 0, stream>>>(dst, (t == 0) ? nullptr : cur,
            sumv + t * CSP, sumq + t * CSP, gam + (size_t)t * CS, bet + (size_t)t * CS,
            (t == 0) ? nullptr : flm + (size_t)(t - 1) * CS);
        cur = dst;
        which ^= 1;
    }
    // layer 6: only the head's 16 selected columns
    __half* h6 = bufs[which];                     // cur == layer-5 output
    gather_k<<<dim3(8, 16, 2), 64, 0, stream>>>(cur, h6,
        ent + (size_t)6 * CSP * KCAP, cnt + 6 * CSP, bb + (size_t)5 * CS,
        sumv + 6 * CSP, sumq + 6 * CSP, hs, hcnt);
    head_k<<<dim3(32), 256, 0, stream>>>(h6, cur, hcnt, hs, hc,
        sumv + 6 * CSP, sumq + 6 * CSP, gam + (size_t)6 * CS, bet + (size_t)6 * CS,
        flm + (size_t)5 * CS, bout, out);
}